// Round 1
// baseline (1230.248 us; speedup 1.0000x reference)
//
#include <hip/hip_runtime.h>

#define NTOK 8192
#define CDIM 1024
#define HDIM 128

typedef __attribute__((ext_vector_type(8))) short short8;
typedef __attribute__((ext_vector_type(4))) float floatx4;

__device__ inline unsigned short f2bf(float f) {
    union { float f; unsigned u; } v; v.f = f;
    unsigned r = v.u + 0x7fffu + ((v.u >> 16) & 1u);
    return (unsigned short)(r >> 16);
}

// ---------------- cast fp32 -> bf16, 4 elems/thread ----------------
__global__ void cast_f32_bf16(const float* __restrict__ in,
                              unsigned short* __restrict__ out, int n4) {
    int i = blockIdx.x * blockDim.x + threadIdx.x;
    if (i < n4) {
        float4 v = ((const float4*)in)[i];
        ushort4 o;
        o.x = f2bf(v.x); o.y = f2bf(v.y); o.z = f2bf(v.z); o.w = f2bf(v.w);
        ((ushort4*)out)[i] = o;
    }
}

// ---------------- NT GEMM: out = A[MxK] @ W[NxK]^T + bias ----------------
// MODE 0: f32 out row-major; MODE 1: bf16 out row-major; MODE 2: bf16 out transposed [N][M]
template<int MODE>
__global__ __launch_bounds__(256) void gemm_nt(
    const unsigned short* __restrict__ A, const unsigned short* __restrict__ W,
    const float* __restrict__ bias, void* __restrict__ out, int M, int N, int K)
{
    __shared__ short As[4][64][8]; // [k-chunk][m-local][8]
    __shared__ short Ws[4][64][8]; // [k-chunk][n-local][8]
    const int tid = threadIdx.x;
    const int wave = tid >> 6, lane = tid & 63;
    const int lr = lane & 15, lc = lane >> 4;
    const int m0 = blockIdx.x * 64, n0 = blockIdx.y * 64;

    floatx4 acc[4] = {};
    const int srow = tid >> 2, sch = tid & 3;
    const unsigned short* Ag = A + (long)(m0 + srow) * K + sch * 8;
    const unsigned short* Wg = W + (long)(n0 + srow) * K + sch * 8;

    for (int k0 = 0; k0 < K; k0 += 32) {
        *(short8*)&As[sch][srow][0] = *(const short8*)(Ag + k0);
        *(short8*)&Ws[sch][srow][0] = *(const short8*)(Wg + k0);
        __syncthreads();
        short8 a = *(short8*)&As[lc][wave * 16 + lr][0];
#pragma unroll
        for (int s = 0; s < 4; s++) {
            short8 b = *(short8*)&Ws[lc][s * 16 + lr][0];
            acc[s] = __builtin_amdgcn_mfma_f32_16x16x32_bf16(a, b, acc[s], 0, 0, 0);
        }
        __syncthreads();
    }

#pragma unroll
    for (int s = 0; s < 4; s++) {
        int n = n0 + s * 16 + lr;
        float bv = bias[n];
        int mbase = m0 + wave * 16 + lc * 4;
        if (MODE == 0) {
            float* o = (float*)out;
#pragma unroll
            for (int r = 0; r < 4; r++) o[(long)(mbase + r) * N + n] = acc[s][r] + bv;
        } else if (MODE == 1) {
            unsigned short* o = (unsigned short*)out;
#pragma unroll
            for (int r = 0; r < 4; r++) o[(long)(mbase + r) * N + n] = f2bf(acc[s][r] + bv);
        } else {
            unsigned short* o = (unsigned short*)out;
            ushort4 pk;
            pk.x = f2bf(acc[s][0] + bv); pk.y = f2bf(acc[s][1] + bv);
            pk.z = f2bf(acc[s][2] + bv); pk.w = f2bf(acc[s][3] + bv);
            *(ushort4*)&o[(long)n * M + mbase] = pk;
        }
    }
}

// ---------------- pass 1: row max / row sum of exp over scores ----------------
__global__ __launch_bounds__(256) void attn_stats(
    const unsigned short* __restrict__ qb, const unsigned short* __restrict__ kb,
    float* __restrict__ row_max, float* __restrict__ row_sum)
{
    const int tid = threadIdx.x, wave = tid >> 6, lane = tid & 63;
    const int lr = lane & 15, lc = lane >> 4;
    const int mbase = (blockIdx.x * 4 + wave) * 16;
    const float scale = 0.08838834764831845f; // 1/sqrt(128)

    short8 qf[4];
#pragma unroll
    for (int kk = 0; kk < 4; kk++)
        qf[kk] = *(const short8*)&qb[(mbase + lr) * HDIM + kk * 32 + lc * 8];

    float m[4] = {-1e30f, -1e30f, -1e30f, -1e30f};
    float l[4] = {0.f, 0.f, 0.f, 0.f};

    for (int n0 = 0; n0 < NTOK; n0 += 16) {
        floatx4 acc = {};
#pragma unroll
        for (int kk = 0; kk < 4; kk++) {
            short8 b = *(const short8*)&kb[(n0 + lr) * HDIM + kk * 32 + lc * 8];
            acc = __builtin_amdgcn_mfma_f32_16x16x32_bf16(qf[kk], b, acc, 0, 0, 0);
        }
#pragma unroll
        for (int r = 0; r < 4; r++) {
            float s = acc[r] * scale;
            float tm = s;
#pragma unroll
            for (int off = 1; off < 16; off <<= 1) tm = fmaxf(tm, __shfl_xor(tm, off));
            float nm = fmaxf(m[r], tm);
            float e = __expf(s - nm);
#pragma unroll
            for (int off = 1; off < 16; off <<= 1) e += __shfl_xor(e, off);
            l[r] = l[r] * __expf(m[r] - nm) + e;
            m[r] = nm;
        }
    }
    if (lr == 0) {
#pragma unroll
        for (int r = 0; r < 4; r++) {
            row_max[mbase + lc * 4 + r] = m[r];
            row_sum[mbase + lc * 4 + r] = l[r];
        }
    }
}

// ---------------- pass 2: O = softmax(S) @ V for a 64x256 output tile ----------------
__global__ __launch_bounds__(256) void attn_pv(
    const unsigned short* __restrict__ qb, const unsigned short* __restrict__ kb,
    const unsigned short* __restrict__ vt, const float* __restrict__ row_max,
    const float* __restrict__ row_sum, unsigned short* __restrict__ attn_out)
{
    __shared__ short Ks[16][32][8];   // [hd-chunk][n-local][8]
    __shared__ short Vs[4][256][8];   // [n-chunk][c-local][8]
    __shared__ short Ps[4][4][16][8]; // [wave][n-chunk][m-local][8]

    const int tid = threadIdx.x, wave = tid >> 6, lane = tid & 63;
    const int lr = lane & 15, lc = lane >> 4;
    const int m0 = blockIdx.x * 64, c0 = blockIdx.y * 256;
    const int mw = m0 + wave * 16;
    const float scale = 0.08838834764831845f;

    short8 qf[4];
#pragma unroll
    for (int kk = 0; kk < 4; kk++)
        qf[kk] = *(const short8*)&qb[(mw + lr) * HDIM + kk * 32 + lc * 8];

    float mrow[4], isum[4];
#pragma unroll
    for (int r = 0; r < 4; r++) {
        int mi = mw + lc * 4 + r;
        mrow[r] = row_max[mi];
        isum[r] = 1.0f / row_sum[mi];
    }

    floatx4 acc[16] = {};

    for (int n0 = 0; n0 < NTOK; n0 += 32) {
        // stage K tile: 32 rows x 128 hd (8 KB)
#pragma unroll
        for (int i = 0; i < 2; i++) {
            int s = tid + i * 256;
            int row = s >> 4, ch = s & 15;
            *(short8*)&Ks[ch][row][0] = *(const short8*)&kb[(n0 + row) * HDIM + ch * 8];
        }
        // stage V tile from v^T: 256 c-rows x 32 n (16 KB)
#pragma unroll
        for (int i = 0; i < 4; i++) {
            int s = tid + i * 256;
            int c = s >> 2, ch = s & 3;
            *(short8*)&Vs[ch][c][0] = *(const short8*)&vt[(long)(c0 + c) * NTOK + n0 + ch * 8];
        }
        __syncthreads();

        // S = q @ k^T (16x32 per wave) -> P = exp(s*scale - rowmax) -> LDS (bf16, A-layout)
#pragma unroll
        for (int sub = 0; sub < 2; sub++) {
            floatx4 sa = {};
#pragma unroll
            for (int kk = 0; kk < 4; kk++) {
                short8 b = *(short8*)&Ks[kk * 4 + lc][sub * 16 + lr][0];
                sa = __builtin_amdgcn_mfma_f32_16x16x32_bf16(qf[kk], b, sa, 0, 0, 0);
            }
            int ncol = sub * 16 + lr;
#pragma unroll
            for (int r = 0; r < 4; r++) {
                float p = __expf(sa[r] * scale - mrow[r]);
                Ps[wave][ncol >> 3][lc * 4 + r][ncol & 7] = (short)f2bf(p);
            }
        }
        // PV: O[16x256] += P[16x32] @ V[32x256]
        short8 ap = *(short8*)&Ps[wave][lc][lr][0];
#pragma unroll
        for (int cs = 0; cs < 16; cs++) {
            short8 b = *(short8*)&Vs[lc][cs * 16 + lr][0];
            acc[cs] = __builtin_amdgcn_mfma_f32_16x16x32_bf16(ap, b, acc[cs], 0, 0, 0);
        }
        __syncthreads();
    }

#pragma unroll
    for (int cs = 0; cs < 16; cs++) {
        int c = c0 + cs * 16 + lr;
#pragma unroll
        for (int r = 0; r < 4; r++) {
            attn_out[(long)(mw + lc * 4 + r) * CDIM + c] = f2bf(acc[cs][r] * isum[r]);
        }
    }
}

extern "C" void kernel_launch(void* const* d_in, const int* in_sizes, int n_in,
                              void* d_out, int out_size, void* d_ws, size_t ws_size,
                              hipStream_t stream) {
    const float* x  = (const float*)d_in[0];
    const float* Wq = (const float*)d_in[1];
    const float* bq = (const float*)d_in[2];
    const float* Wk = (const float*)d_in[3];
    const float* bk = (const float*)d_in[4];
    const float* Wv = (const float*)d_in[5];
    const float* bv = (const float*)d_in[6];
    const float* Wo = (const float*)d_in[7];
    const float* bo = (const float*)d_in[8];

    char* ws = (char*)d_ws;
    unsigned short* x_bf   = (unsigned short*)(ws + 0);          // 16 MB
    unsigned short* wq_bf  = (unsigned short*)(ws + 16777216);   // 256 KB
    unsigned short* wk_bf  = (unsigned short*)(ws + 17039360);   // 256 KB
    unsigned short* wv_bf  = (unsigned short*)(ws + 17301504);   // 2 MB
    unsigned short* wo_bf  = (unsigned short*)(ws + 19398656);   // 2 MB
    unsigned short* q_bf   = (unsigned short*)(ws + 21495808);   // 2 MB
    unsigned short* k_bf   = (unsigned short*)(ws + 23592960);   // 2 MB
    unsigned short* vt_bf  = (unsigned short*)(ws + 25690112);   // 16 MB (transposed: [C][N])
    unsigned short* attn_bf= (unsigned short*)(ws + 42467328);   // 16 MB
    float* row_max         = (float*)(ws + 59244544);            // 32 KB
    float* row_sum         = (float*)(ws + 59277312);            // 32 KB

    // casts to bf16
    cast_f32_bf16<<<8192, 256, 0, stream>>>(x,  x_bf,  2097152);
    cast_f32_bf16<<<128,  256, 0, stream>>>(Wq, wq_bf, 32768);
    cast_f32_bf16<<<128,  256, 0, stream>>>(Wk, wk_bf, 32768);
    cast_f32_bf16<<<1024, 256, 0, stream>>>(Wv, wv_bf, 262144);
    cast_f32_bf16<<<1024, 256, 0, stream>>>(Wo, wo_bf, 262144);

    // projections
    gemm_nt<1><<<dim3(128, 2),  256, 0, stream>>>(x_bf, wq_bf, bq, q_bf, NTOK, HDIM, CDIM);
    gemm_nt<1><<<dim3(128, 2),  256, 0, stream>>>(x_bf, wk_bf, bk, k_bf, NTOK, HDIM, CDIM);
    gemm_nt<2><<<dim3(128, 16), 256, 0, stream>>>(x_bf, wv_bf, bv, vt_bf, NTOK, CDIM, CDIM);

    // attention
    attn_stats<<<128, 256, 0, stream>>>(q_bf, k_bf, row_max, row_sum);
    attn_pv<<<dim3(128, 4), 256, 0, stream>>>(q_bf, k_bf, vt_bf, row_max, row_sum, attn_bf);

    // output projection (fp32 out)
    gemm_nt<0><<<dim3(128, 16), 256, 0, stream>>>(attn_bf, wo_bf, bo, d_out, NTOK, CDIM, CDIM);
}

// Round 2
// 671.559 us; speedup vs baseline: 1.8319x; 1.8319x over previous
//
#include <hip/hip_runtime.h>

#define NTOK 8192
#define CDIM 1024
#define HDIM 128

typedef __attribute__((ext_vector_type(8))) short short8;
typedef __attribute__((ext_vector_type(4))) float floatx4;

__device__ inline unsigned short f2bf(float f) {
    union { float f; unsigned u; } v; v.f = f;
    unsigned r = v.u + 0x7fffu + ((v.u >> 16) & 1u);
    return (unsigned short)(r >> 16);
}
__device__ inline float bf2f(short s) {
    union { unsigned u; float f; } v;
    v.u = ((unsigned)(unsigned short)s) << 16;
    return v.f;
}
__device__ inline void async16(const unsigned short* g, short* l) {
    __builtin_amdgcn_global_load_lds(
        (const __attribute__((address_space(1))) unsigned*)g,
        (__attribute__((address_space(3))) unsigned*)l, 16, 0, 0);
}

// ---------------- cast fp32 -> bf16, 4 elems/thread ----------------
__global__ void cast_f32_bf16(const float* __restrict__ in,
                              unsigned short* __restrict__ out, int n4) {
    int i = blockIdx.x * blockDim.x + threadIdx.x;
    if (i < n4) {
        float4 v = ((const float4*)in)[i];
        ushort4 o;
        o.x = f2bf(v.x); o.y = f2bf(v.y); o.z = f2bf(v.z); o.w = f2bf(v.w);
        ((ushort4*)out)[i] = o;
    }
}

// ---------------- 64-tile NT GEMM (for narrow N: q/k proj) ----------------
// MODE 1: bf16 out row-major
__global__ __launch_bounds__(256) void gemm_nt(
    const unsigned short* __restrict__ A, const unsigned short* __restrict__ W,
    const float* __restrict__ bias, unsigned short* __restrict__ out, int M, int N, int K)
{
    __shared__ short As[4][64][8];
    __shared__ short Ws[4][64][8];
    const int tid = threadIdx.x;
    const int wave = tid >> 6, lane = tid & 63;
    const int lr = lane & 15, lc = lane >> 4;
    const int m0 = blockIdx.x * 64, n0 = blockIdx.y * 64;

    floatx4 acc[4] = {};
    const int srow = tid >> 2, sch = tid & 3;
    const unsigned short* Ag = A + (long)(m0 + srow) * K + sch * 8;
    const unsigned short* Wg = W + (long)(n0 + srow) * K + sch * 8;

    for (int k0 = 0; k0 < K; k0 += 32) {
        *(short8*)&As[sch][srow][0] = *(const short8*)(Ag + k0);
        *(short8*)&Ws[sch][srow][0] = *(const short8*)(Wg + k0);
        __syncthreads();
        short8 a = *(short8*)&As[lc][wave * 16 + lr][0];
#pragma unroll
        for (int s = 0; s < 4; s++) {
            short8 b = *(short8*)&Ws[lc][s * 16 + lr][0];
            acc[s] = __builtin_amdgcn_mfma_f32_16x16x32_bf16(a, b, acc[s], 0, 0, 0);
        }
        __syncthreads();
    }

#pragma unroll
    for (int s = 0; s < 4; s++) {
        int n = n0 + s * 16 + lr;
        float bv = bias[n];
        int mbase = m0 + wave * 16 + lc * 4;
#pragma unroll
        for (int r = 0; r < 4; r++) out[(long)(mbase + r) * N + n] = f2bf(acc[s][r] + bv);
    }
}

// ---------------- 128-tile NT GEMM, m97-style (global_load_lds staging) ----------------
// MODE 0: f32 out row-major; MODE 2: bf16 out transposed [N][M]
template<int MODE>
__global__ __launch_bounds__(256) void gemm128_nt(
    const unsigned short* __restrict__ A, const unsigned short* __restrict__ W,
    const float* __restrict__ bias, void* __restrict__ out, int M, int N, int K)
{
    __shared__ short As[128][4][8]; // [row][k-chunk][8]
    __shared__ short Ws[128][4][8];
    const int tid = threadIdx.x, wave = tid >> 6, lane = tid & 63;
    const int lr = lane & 15, lc = lane >> 4;
    const int wm = (wave >> 1) * 64, wn = (wave & 1) * 64;
    const int m0 = blockIdx.x * 128, n0 = blockIdx.y * 128;

    floatx4 acc[4][4] = {};

    const int srow = lane >> 2, sch = lane & 3; // staging: 16 rows x 4 chunks per wave-load
    const unsigned short* Ag0 = A + (long)(m0 + wave * 32 + srow) * K + sch * 8;
    const unsigned short* Ag1 = Ag0 + (long)16 * K;
    const unsigned short* Wg0 = W + (long)(n0 + wave * 32 + srow) * K + sch * 8;
    const unsigned short* Wg1 = Wg0 + (long)16 * K;
    short* lA0 = &As[wave * 32][0][0];
    short* lA1 = &As[wave * 32 + 16][0][0];
    short* lW0 = &Ws[wave * 32][0][0];
    short* lW1 = &Ws[wave * 32 + 16][0][0];

    for (int k0 = 0; k0 < K; k0 += 32) {
        async16(Ag0 + k0, lA0);
        async16(Ag1 + k0, lA1);
        async16(Wg0 + k0, lW0);
        async16(Wg1 + k0, lW1);
        __syncthreads();
        short8 af[4], bfg[4];
#pragma unroll
        for (int i = 0; i < 4; i++) af[i]  = *(short8*)&As[wm + i * 16 + lr][lc][0];
#pragma unroll
        for (int j = 0; j < 4; j++) bfg[j] = *(short8*)&Ws[wn + j * 16 + lr][lc][0];
#pragma unroll
        for (int i = 0; i < 4; i++)
#pragma unroll
            for (int j = 0; j < 4; j++)
                acc[i][j] = __builtin_amdgcn_mfma_f32_16x16x32_bf16(af[i], bfg[j], acc[i][j], 0, 0, 0);
        __syncthreads();
    }

#pragma unroll
    for (int i = 0; i < 4; i++) {
        int mbase = m0 + wm + i * 16 + lc * 4;
#pragma unroll
        for (int j = 0; j < 4; j++) {
            int n = n0 + wn + j * 16 + lr;
            float bv = bias[n];
            if (MODE == 0) {
                float* o = (float*)out;
#pragma unroll
                for (int r = 0; r < 4; r++) o[(long)(mbase + r) * N + n] = acc[i][j][r] + bv;
            } else {
                unsigned short* o = (unsigned short*)out;
                ushort4 pk;
                pk.x = f2bf(acc[i][j][0] + bv); pk.y = f2bf(acc[i][j][1] + bv);
                pk.z = f2bf(acc[i][j][2] + bv); pk.w = f2bf(acc[i][j][3] + bv);
                *(ushort4*)&o[(long)n * M + mbase] = pk;
            }
        }
    }
}

// ---------------- fused attention: partial O = exp(QK^T*scale) @ V, partial rowsum ----------------
// grid (m-tiles=128, c-tiles=4, n-split=2); block 64m x 256c; no max subtraction.
__global__ __launch_bounds__(256) void attn_pv(
    const unsigned short* __restrict__ qb, const unsigned short* __restrict__ kb,
    const unsigned short* __restrict__ vt,
    unsigned short* __restrict__ Oa, unsigned short* __restrict__ Ob,
    float* __restrict__ la, float* __restrict__ lb)
{
    __shared__ short Ks[16][32][8];   // [hd-chunk][n-local][8]
    __shared__ short Vs[4][256][8];   // [n-chunk][c-local][8]
    __shared__ short Ps[4][4][16][8]; // [wave][n-chunk][m-local][8]

    const int tid = threadIdx.x, wave = tid >> 6, lane = tid & 63;
    const int lr = lane & 15, lc = lane >> 4;
    const int m0 = blockIdx.x * 64, c0 = blockIdx.y * 256;
    const int mw = m0 + wave * 16;
    const int nbase = blockIdx.z * (NTOK / 2);
    unsigned short* Op = blockIdx.z ? Ob : Oa;
    float* ls = blockIdx.z ? lb : la;
    const float scale = 0.08838834764831845f;

    short8 qf[4];
#pragma unroll
    for (int kk = 0; kk < 4; kk++)
        qf[kk] = *(const short8*)&qb[(mw + lr) * HDIM + kk * 32 + lc * 8];

    floatx4 acc[16] = {};
    float lsum[4] = {0.f, 0.f, 0.f, 0.f};

    // staging descriptors (global_load_lds, wave-uniform LDS base + lane*16)
    // Ks: 8 wave-loads of 1024B; load L covers chunks {2L,2L+1} x 32 rows
    const int kL = wave * 2;
    const unsigned short* kg[2]; short* kl[2];
#pragma unroll
    for (int t = 0; t < 2; t++) {
        int L = kL + t;
        int ch = 2 * L + (lane >> 5), row = lane & 31;
        kg[t] = kb + (long)row * HDIM + ch * 8;
        kl[t] = &Ks[2 * L][0][0];
    }
    // Vs: 16 wave-loads of 1024B; load L covers chunk L>>2, c-range (L&3)*64
    const unsigned short* vg[4]; short* vl[4];
#pragma unroll
    for (int t = 0; t < 4; t++) {
        int L = wave * 4 + t;
        int ch = L >> 2, cb = (L & 3) * 64;
        vg[t] = vt + (long)(c0 + cb + lane) * NTOK + ch * 8;
        vl[t] = &Vs[ch][cb][0];
    }

    for (int n0 = nbase; n0 < nbase + NTOK / 2; n0 += 32) {
#pragma unroll
        for (int t = 0; t < 2; t++) async16(kg[t] + (long)n0 * HDIM, kl[t]);
#pragma unroll
        for (int t = 0; t < 4; t++) async16(vg[t] + n0, vl[t]);
        __syncthreads();

        // S = q @ k^T (16x32 per wave) -> P = exp(s*scale) -> LDS (bf16, A-layout)
#pragma unroll
        for (int sub = 0; sub < 2; sub++) {
            floatx4 sa = {};
#pragma unroll
            for (int kk = 0; kk < 4; kk++) {
                short8 b = *(short8*)&Ks[kk * 4 + lc][sub * 16 + lr][0];
                sa = __builtin_amdgcn_mfma_f32_16x16x32_bf16(qf[kk], b, sa, 0, 0, 0);
            }
            int ncol = sub * 16 + lr;
#pragma unroll
            for (int r = 0; r < 4; r++) {
                float p = __expf(sa[r] * scale);
                lsum[r] += p;
                Ps[wave][ncol >> 3][lc * 4 + r][ncol & 7] = (short)f2bf(p);
            }
        }
        // PV: O[16x256] += P[16x32] @ V[32x256]
        short8 ap = *(short8*)&Ps[wave][lc][lr][0];
#pragma unroll
        for (int cs = 0; cs < 16; cs++) {
            short8 b = *(short8*)&Vs[lc][cs * 16 + lr][0];
            acc[cs] = __builtin_amdgcn_mfma_f32_16x16x32_bf16(ap, b, acc[cs], 0, 0, 0);
        }
        __syncthreads();
    }

    // unnormalized partial O
#pragma unroll
    for (int cs = 0; cs < 16; cs++) {
        int c = c0 + cs * 16 + lr;
#pragma unroll
        for (int r = 0; r < 4; r++)
            Op[(long)(mw + lc * 4 + r) * CDIM + c] = f2bf(acc[cs][r]);
    }
    // partial row sums (only one c-tile writes; reduce across lr lanes)
    if (blockIdx.y == 0) {
#pragma unroll
        for (int r = 0; r < 4; r++) {
#pragma unroll
            for (int off = 1; off < 16; off <<= 1) lsum[r] += __shfl_xor(lsum[r], off);
        }
        if (lr == 0) {
#pragma unroll
            for (int r = 0; r < 4; r++) ls[mw + lc * 4 + r] = lsum[r];
        }
    }
}

// ---------------- combine: attn = (Oa + Ob) / (la + lb), in place over Ob ----------------
__global__ __launch_bounds__(256) void combine_attn(
    const unsigned short* __restrict__ Oa, unsigned short* __restrict__ Ob,
    const float* __restrict__ la, const float* __restrict__ lb)
{
    int i = blockIdx.x * blockDim.x + threadIdx.x; // one per 8 elems
    int row = i >> 7;                              // CDIM/8 = 128
    float inv = 1.0f / (la[row] + lb[row]);
    short8 a = ((const short8*)Oa)[i];
    short8 b = ((const short8*)Ob)[i];
    short8 o;
#pragma unroll
    for (int e = 0; e < 8; e++) o[e] = (short)f2bf((bf2f(a[e]) + bf2f(b[e])) * inv);
    ((short8*)Ob)[i] = o;
}

extern "C" void kernel_launch(void* const* d_in, const int* in_sizes, int n_in,
                              void* d_out, int out_size, void* d_ws, size_t ws_size,
                              hipStream_t stream) {
    const float* x  = (const float*)d_in[0];
    const float* Wq = (const float*)d_in[1];
    const float* bq = (const float*)d_in[2];
    const float* Wk = (const float*)d_in[3];
    const float* bk = (const float*)d_in[4];
    const float* Wv = (const float*)d_in[5];
    const float* bv = (const float*)d_in[6];
    const float* Wo = (const float*)d_in[7];
    const float* bo = (const float*)d_in[8];

    char* ws = (char*)d_ws;
    unsigned short* x_bf   = (unsigned short*)(ws + 0);          // 16 MB (reused as Oa after projections)
    unsigned short* wq_bf  = (unsigned short*)(ws + 16777216);   // 256 KB
    unsigned short* wk_bf  = (unsigned short*)(ws + 17039360);   // 256 KB
    unsigned short* wv_bf  = (unsigned short*)(ws + 17301504);   // 2 MB
    unsigned short* wo_bf  = (unsigned short*)(ws + 19398656);   // 2 MB
    unsigned short* q_bf   = (unsigned short*)(ws + 21495808);   // 2 MB
    unsigned short* k_bf   = (unsigned short*)(ws + 23592960);   // 2 MB
    unsigned short* vt_bf  = (unsigned short*)(ws + 25690112);   // 16 MB (transposed: [C][N])
    unsigned short* attn_bf= (unsigned short*)(ws + 42467328);   // 16 MB (Ob, combined in place)
    float* lsum_a          = (float*)(ws + 59244544);            // 32 KB
    float* lsum_b          = (float*)(ws + 59277312);            // 32 KB

    // casts to bf16
    cast_f32_bf16<<<8192, 256, 0, stream>>>(x,  x_bf,  2097152);
    cast_f32_bf16<<<128,  256, 0, stream>>>(Wq, wq_bf, 32768);
    cast_f32_bf16<<<128,  256, 0, stream>>>(Wk, wk_bf, 32768);
    cast_f32_bf16<<<1024, 256, 0, stream>>>(Wv, wv_bf, 262144);
    cast_f32_bf16<<<1024, 256, 0, stream>>>(Wo, wo_bf, 262144);

    // projections
    gemm_nt<<<dim3(128, 2), 256, 0, stream>>>(x_bf, wq_bf, bq, q_bf, NTOK, HDIM, CDIM);
    gemm_nt<<<dim3(128, 2), 256, 0, stream>>>(x_bf, wk_bf, bk, k_bf, NTOK, HDIM, CDIM);
    gemm128_nt<2><<<dim3(64, 8), 256, 0, stream>>>(x_bf, wv_bf, bv, vt_bf, NTOK, CDIM, CDIM);

    // fused attention (split-n over gridDim.z); Oa overlays dead x_bf
    attn_pv<<<dim3(128, 4, 2), 256, 0, stream>>>(q_bf, k_bf, vt_bf,
                                                 x_bf, attn_bf, lsum_a, lsum_b);
    combine_attn<<<4096, 256, 0, stream>>>(x_bf, attn_bf, lsum_a, lsum_b);

    // output projection (fp32 out)
    gemm128_nt<0><<<dim3(64, 8), 256, 0, stream>>>(attn_bf, wo_bf, bo, d_out, NTOK, CDIM, CDIM);
}

// Round 3
// 606.183 us; speedup vs baseline: 2.0295x; 1.1078x over previous
//
#include <hip/hip_runtime.h>

#define NTOK 8192
#define CDIM 1024
#define HDIM 128

typedef __attribute__((ext_vector_type(8))) short short8;
typedef __attribute__((ext_vector_type(4))) float floatx4;

__device__ inline unsigned short f2bf(float f) {
    union { float f; unsigned u; } v; v.f = f;
    unsigned r = v.u + 0x7fffu + ((v.u >> 16) & 1u);
    return (unsigned short)(r >> 16);
}
__device__ inline float bf2f(short s) {
    union { unsigned u; float f; } v;
    v.u = ((unsigned)(unsigned short)s) << 16;
    return v.f;
}
__device__ inline void async16(const unsigned short* g, short* l) {
    __builtin_amdgcn_global_load_lds(
        (const __attribute__((address_space(1))) unsigned*)g,
        (__attribute__((address_space(3))) unsigned*)l, 16, 0, 0);
}

// ---------------- cast fp32 -> bf16, 4 elems/thread ----------------
__global__ void cast_f32_bf16(const float* __restrict__ in,
                              unsigned short* __restrict__ out, int n4) {
    int i = blockIdx.x * blockDim.x + threadIdx.x;
    if (i < n4) {
        float4 v = ((const float4*)in)[i];
        ushort4 o;
        o.x = f2bf(v.x); o.y = f2bf(v.y); o.z = f2bf(v.z); o.w = f2bf(v.w);
        ((ushort4*)out)[i] = o;
    }
}

// ---------------- 64-tile NT GEMM (narrow N: q/k proj) ----------------
// SWZ=0: bf16 row-major out. SWZ=1: K-swizzled out [tok>>5][hd>>3][tok&31][hd&7]
template<int SWZ>
__global__ __launch_bounds__(256) void gemm_nt(
    const unsigned short* __restrict__ A, const unsigned short* __restrict__ W,
    const float* __restrict__ bias, unsigned short* __restrict__ out, int M, int N, int K)
{
    __shared__ short As[4][64][8];
    __shared__ short Ws[4][64][8];
    const int tid = threadIdx.x;
    const int wave = tid >> 6, lane = tid & 63;
    const int lr = lane & 15, lc = lane >> 4;
    const int m0 = blockIdx.x * 64, n0 = blockIdx.y * 64;

    floatx4 acc[4] = {};
    const int srow = tid >> 2, sch = tid & 3;
    const unsigned short* Ag = A + (long)(m0 + srow) * K + sch * 8;
    const unsigned short* Wg = W + (long)(n0 + srow) * K + sch * 8;

    for (int k0 = 0; k0 < K; k0 += 32) {
        *(short8*)&As[sch][srow][0] = *(const short8*)(Ag + k0);
        *(short8*)&Ws[sch][srow][0] = *(const short8*)(Wg + k0);
        __syncthreads();
        short8 a = *(short8*)&As[lc][wave * 16 + lr][0];
#pragma unroll
        for (int s = 0; s < 4; s++) {
            short8 b = *(short8*)&Ws[lc][s * 16 + lr][0];
            acc[s] = __builtin_amdgcn_mfma_f32_16x16x32_bf16(a, b, acc[s], 0, 0, 0);
        }
        __syncthreads();
    }

#pragma unroll
    for (int s = 0; s < 4; s++) {
        int h = n0 + s * 16 + lr;
        float bv = bias[h];
        int tok0 = m0 + wave * 16 + lc * 4;
#pragma unroll
        for (int r = 0; r < 4; r++) {
            int tok = tok0 + r;
            if (SWZ)
                out[(tok >> 5) * 4096 + (h >> 3) * 256 + (tok & 31) * 8 + (h & 7)] =
                    f2bf(acc[s][r] + bv);
            else
                out[(long)tok * N + h] = f2bf(acc[s][r] + bv);
        }
    }
}

// ---------------- 128-tile NT GEMM, global_load_lds staging ----------------
// MODE 0: f32 out row-major; MODE 2: V-swizzled bf16 out
template<int MODE>
__global__ __launch_bounds__(256) void gemm128_nt(
    const unsigned short* __restrict__ A, const unsigned short* __restrict__ W,
    const float* __restrict__ bias, void* __restrict__ out, int M, int N, int K)
{
    __shared__ short As[128][4][8]; // [row][k-chunk][8]
    __shared__ short Ws[128][4][8];
    const int tid = threadIdx.x, wave = tid >> 6, lane = tid & 63;
    const int lr = lane & 15, lc = lane >> 4;
    const int wm = (wave >> 1) * 64, wn = (wave & 1) * 64;
    const int m0 = blockIdx.x * 128, n0 = blockIdx.y * 128;

    floatx4 acc[4][4] = {};

    const int srow = lane >> 2, sch = lane & 3;
    const unsigned short* Ag0 = A + (long)(m0 + wave * 32 + srow) * K + sch * 8;
    const unsigned short* Ag1 = Ag0 + (long)16 * K;
    const unsigned short* Wg0 = W + (long)(n0 + wave * 32 + srow) * K + sch * 8;
    const unsigned short* Wg1 = Wg0 + (long)16 * K;
    short* lA0 = &As[wave * 32][0][0];
    short* lA1 = &As[wave * 32 + 16][0][0];
    short* lW0 = &Ws[wave * 32][0][0];
    short* lW1 = &Ws[wave * 32 + 16][0][0];

    for (int k0 = 0; k0 < K; k0 += 32) {
        async16(Ag0 + k0, lA0);
        async16(Ag1 + k0, lA1);
        async16(Wg0 + k0, lW0);
        async16(Wg1 + k0, lW1);
        __syncthreads();
        short8 af[4], bfg[4];
#pragma unroll
        for (int i = 0; i < 4; i++) af[i]  = *(short8*)&As[wm + i * 16 + lr][lc][0];
#pragma unroll
        for (int j = 0; j < 4; j++) bfg[j] = *(short8*)&Ws[wn + j * 16 + lr][lc][0];
#pragma unroll
        for (int i = 0; i < 4; i++)
#pragma unroll
            for (int j = 0; j < 4; j++)
                acc[i][j] = __builtin_amdgcn_mfma_f32_16x16x32_bf16(af[i], bfg[j], acc[i][j], 0, 0, 0);
        __syncthreads();
    }

#pragma unroll
    for (int i = 0; i < 4; i++) {
        int t0 = m0 + wm + i * 16 + lc * 4;
#pragma unroll
        for (int j = 0; j < 4; j++) {
            int c = n0 + wn + j * 16 + lr;
            float bv = bias[c];
            if (MODE == 0) {
                float* o = (float*)out;
#pragma unroll
                for (int r = 0; r < 4; r++) o[(long)(t0 + r) * N + c] = acc[i][j][r] + bv;
            } else {
                unsigned short* o = (unsigned short*)out;
                ushort4 pk;
                pk.x = f2bf(acc[i][j][0] + bv); pk.y = f2bf(acc[i][j][1] + bv);
                pk.z = f2bf(acc[i][j][2] + bv); pk.w = f2bf(acc[i][j][3] + bv);
                long off = (long)(c >> 8) * 2097152 + (t0 >> 5) * 8192 +
                           ((t0 & 31) >> 3) * 2048 + (c & 255) * 8 + (t0 & 7);
                *(ushort4*)&o[off] = pk;
            }
        }
    }
}

// ---------------- fused attention: partial O = exp(QK^T*scale) @ V + rowsum ----------------
// grid (m-tiles=64, c-tiles=4, n-split=2); block: 4 waves x 32 rows = 128 rows, 256 c.
// K_swz: [ntile][ch16][row32][8] tiles of 8KB; V_swz: [cblk][ntile][ch4][c256][8] tiles of 16KB.
__global__ __launch_bounds__(256) void attn_pv(
    const unsigned short* __restrict__ qb, const unsigned short* __restrict__ ksw,
    const unsigned short* __restrict__ vsw,
    unsigned short* __restrict__ Oa, unsigned short* __restrict__ Ob,
    float* __restrict__ la, float* __restrict__ lb)
{
    __shared__ short Ks[16][32][8];   // 8 KB
    __shared__ short Vs[4][256][8];   // 16 KB
    __shared__ short Ps[4][4][32][8]; // 8 KB [wave][n-chunk][m-local 32][8]

    const int tid = threadIdx.x, wave = tid >> 6, lane = tid & 63;
    const int lr = lane & 15, lc = lane >> 4;
    const int m0 = blockIdx.x * 128, cblk = blockIdx.y;
    const int mw = m0 + wave * 32;
    const int nt0 = blockIdx.z * 128; // 32-wide n-tiles
    unsigned short* Op = blockIdx.z ? Ob : Oa;
    float* ls = blockIdx.z ? lb : la;
    const float scale = 0.08838834764831845f;

    short8 qf[2][4];
#pragma unroll
    for (int i = 0; i < 2; i++)
#pragma unroll
        for (int kk = 0; kk < 4; kk++)
            qf[i][kk] = *(const short8*)&qb[(mw + i * 16 + lr) * HDIM + kk * 32 + lc * 8];

    floatx4 acc[2][16] = {};
    float lsum[2][4] = {};

    // contiguous staging: each wave-load = 64 lanes x 16 B = 1 KB contiguous
    const unsigned short* kg[2]; short* kl[2];
#pragma unroll
    for (int t = 0; t < 2; t++) {
        int L = wave * 2 + t;
        kg[t] = ksw + L * 512 + lane * 8;
        kl[t] = &Ks[0][0][0] + L * 512;
    }
    const unsigned short* vg[4]; short* vl[4];
#pragma unroll
    for (int t = 0; t < 4; t++) {
        int L = wave * 4 + t;
        vg[t] = vsw + (long)cblk * 2097152 + L * 512 + lane * 8;
        vl[t] = &Vs[0][0][0] + L * 512;
    }

    for (int nt = nt0; nt < nt0 + 128; nt++) {
#pragma unroll
        for (int t = 0; t < 2; t++) async16(kg[t] + nt * 4096, kl[t]);
#pragma unroll
        for (int t = 0; t < 4; t++) async16(vg[t] + nt * 8192, vl[t]);
        __syncthreads();

        // S tiles (32 rows x 32 cols per wave) -> P = exp(s*scale) -> Ps (A-layout)
#pragma unroll
        for (int sub = 0; sub < 2; sub++) {
            floatx4 sa0 = {}, sa1 = {};
#pragma unroll
            for (int kk = 0; kk < 4; kk++) {
                short8 b = *(short8*)&Ks[kk * 4 + lc][sub * 16 + lr][0];
                sa0 = __builtin_amdgcn_mfma_f32_16x16x32_bf16(qf[0][kk], b, sa0, 0, 0, 0);
                sa1 = __builtin_amdgcn_mfma_f32_16x16x32_bf16(qf[1][kk], b, sa1, 0, 0, 0);
            }
            int ncol = sub * 16 + lr;
#pragma unroll
            for (int r = 0; r < 4; r++) {
                float p0 = __expf(sa0[r] * scale);
                float p1 = __expf(sa1[r] * scale);
                lsum[0][r] += p0;
                lsum[1][r] += p1;
                Ps[wave][ncol >> 3][lc * 4 + r][ncol & 7] = (short)f2bf(p0);
                Ps[wave][ncol >> 3][16 + lc * 4 + r][ncol & 7] = (short)f2bf(p1);
            }
        }
        // PV: O[32x256] += P[32x32] @ V[32x256]
        short8 ap0 = *(short8*)&Ps[wave][lc][lr][0];
        short8 ap1 = *(short8*)&Ps[wave][lc][16 + lr][0];
#pragma unroll
        for (int cs = 0; cs < 16; cs++) {
            short8 b = *(short8*)&Vs[lc][cs * 16 + lr][0];
            acc[0][cs] = __builtin_amdgcn_mfma_f32_16x16x32_bf16(ap0, b, acc[0][cs], 0, 0, 0);
            acc[1][cs] = __builtin_amdgcn_mfma_f32_16x16x32_bf16(ap1, b, acc[1][cs], 0, 0, 0);
        }
        __syncthreads();
    }

    // unnormalized partial O
#pragma unroll
    for (int i = 0; i < 2; i++)
#pragma unroll
        for (int cs = 0; cs < 16; cs++) {
            int c = cblk * 256 + cs * 16 + lr;
#pragma unroll
            for (int r = 0; r < 4; r++)
                Op[(long)(mw + i * 16 + lc * 4 + r) * CDIM + c] = f2bf(acc[i][cs][r]);
        }
    // partial row sums
    if (blockIdx.y == 0) {
#pragma unroll
        for (int i = 0; i < 2; i++)
#pragma unroll
            for (int r = 0; r < 4; r++) {
#pragma unroll
                for (int off = 1; off < 16; off <<= 1)
                    lsum[i][r] += __shfl_xor(lsum[i][r], off);
            }
        if (lr == 0) {
#pragma unroll
            for (int i = 0; i < 2; i++)
#pragma unroll
                for (int r = 0; r < 4; r++)
                    ls[mw + i * 16 + lc * 4 + r] = lsum[i][r];
        }
    }
}

// ---------------- combine: attn = (Oa + Ob) / (la + lb), in place over Ob ----------------
__global__ __launch_bounds__(256) void combine_attn(
    const unsigned short* __restrict__ Oa, unsigned short* __restrict__ Ob,
    const float* __restrict__ la, const float* __restrict__ lb)
{
    int i = blockIdx.x * blockDim.x + threadIdx.x; // one per 8 elems
    int row = i >> 7;                              // CDIM/8 = 128
    float inv = 1.0f / (la[row] + lb[row]);
    short8 a = ((const short8*)Oa)[i];
    short8 b = ((const short8*)Ob)[i];
    short8 o;
#pragma unroll
    for (int e = 0; e < 8; e++) o[e] = (short)f2bf((bf2f(a[e]) + bf2f(b[e])) * inv);
    ((short8*)Ob)[i] = o;
}

extern "C" void kernel_launch(void* const* d_in, const int* in_sizes, int n_in,
                              void* d_out, int out_size, void* d_ws, size_t ws_size,
                              hipStream_t stream) {
    const float* x  = (const float*)d_in[0];
    const float* Wq = (const float*)d_in[1];
    const float* bq = (const float*)d_in[2];
    const float* Wk = (const float*)d_in[3];
    const float* bk = (const float*)d_in[4];
    const float* Wv = (const float*)d_in[5];
    const float* bv = (const float*)d_in[6];
    const float* Wo = (const float*)d_in[7];
    const float* bo = (const float*)d_in[8];

    char* ws = (char*)d_ws;
    unsigned short* x_bf   = (unsigned short*)(ws + 0);          // 16 MB (reused as Oa)
    unsigned short* wq_bf  = (unsigned short*)(ws + 16777216);   // 256 KB
    unsigned short* wk_bf  = (unsigned short*)(ws + 17039360);   // 256 KB
    unsigned short* wv_bf  = (unsigned short*)(ws + 17301504);   // 2 MB
    unsigned short* wo_bf  = (unsigned short*)(ws + 19398656);   // 2 MB
    unsigned short* q_bf   = (unsigned short*)(ws + 21495808);   // 2 MB
    unsigned short* k_swz  = (unsigned short*)(ws + 23592960);   // 2 MB (K swizzled)
    unsigned short* v_swz  = (unsigned short*)(ws + 25690112);   // 16 MB (V swizzled)
    unsigned short* attn_bf= (unsigned short*)(ws + 42467328);   // 16 MB (Ob, combined in place)
    float* lsum_a          = (float*)(ws + 59244544);            // 32 KB
    float* lsum_b          = (float*)(ws + 59277312);            // 32 KB

    // casts to bf16
    cast_f32_bf16<<<8192, 256, 0, stream>>>(x,  x_bf,  2097152);
    cast_f32_bf16<<<128,  256, 0, stream>>>(Wq, wq_bf, 32768);
    cast_f32_bf16<<<128,  256, 0, stream>>>(Wk, wk_bf, 32768);
    cast_f32_bf16<<<1024, 256, 0, stream>>>(Wv, wv_bf, 262144);
    cast_f32_bf16<<<1024, 256, 0, stream>>>(Wo, wo_bf, 262144);

    // projections
    gemm_nt<0><<<dim3(128, 2), 256, 0, stream>>>(x_bf, wq_bf, bq, q_bf, NTOK, HDIM, CDIM);
    gemm_nt<1><<<dim3(128, 2), 256, 0, stream>>>(x_bf, wk_bf, bk, k_swz, NTOK, HDIM, CDIM);
    gemm128_nt<2><<<dim3(64, 8), 256, 0, stream>>>(x_bf, wv_bf, bv, v_swz, NTOK, CDIM, CDIM);

    // fused attention (split-n over gridDim.z); Oa overlays dead x_bf
    attn_pv<<<dim3(64, 4, 2), 256, 0, stream>>>(q_bf, k_swz, v_swz,
                                                x_bf, attn_bf, lsum_a, lsum_b);
    combine_attn<<<4096, 256, 0, stream>>>(x_bf, attn_bf, lsum_a, lsum_b);

    // output projection (fp32 out)
    gemm128_nt<0><<<dim3(64, 8), 256, 0, stream>>>(attn_bf, wo_bf, bo, d_out, NTOK, CDIM, CDIM);
}

// Round 5
// 598.787 us; speedup vs baseline: 2.0546x; 1.0124x over previous
//
#include <hip/hip_runtime.h>

#define NTOK 8192
#define CDIM 1024
#define HDIM 128

typedef __attribute__((ext_vector_type(8))) short short8;
typedef __attribute__((ext_vector_type(4))) float floatx4;
typedef __attribute__((ext_vector_type(4))) unsigned short ushort4v;

__device__ inline unsigned short f2bf(float f) {
    union { float f; unsigned u; } v; v.f = f;
    unsigned r = v.u + 0x7fffu + ((v.u >> 16) & 1u);
    return (unsigned short)(r >> 16);
}
__device__ inline unsigned short f2bf_fast(float f) {
    union { float f; unsigned u; } v; v.f = f;
    return (unsigned short)((v.u + 0x8000u) >> 16);
}
__device__ inline float bf2f(short s) {
    union { unsigned u; float f; } v;
    v.u = ((unsigned)(unsigned short)s) << 16;
    return v.f;
}
__device__ inline void async16(const unsigned short* g, short* l) {
    __builtin_amdgcn_global_load_lds(
        (const __attribute__((address_space(1))) unsigned*)g,
        (__attribute__((address_space(3))) unsigned*)l, 16, 0, 0);
}

// ---------------- cast fp32 -> bf16, 4 elems/thread ----------------
__global__ void cast_f32_bf16(const float* __restrict__ in,
                              unsigned short* __restrict__ out, int n4) {
    int i = blockIdx.x * blockDim.x + threadIdx.x;
    if (i < n4) {
        float4 v = ((const float4*)in)[i];
        ushort4 o;
        o.x = f2bf(v.x); o.y = f2bf(v.y); o.z = f2bf(v.z); o.w = f2bf(v.w);
        ((ushort4*)out)[i] = o;
    }
}

// ---------------- 64-tile NT GEMM (narrow N: q/k proj) ----------------
// SWZ=0: bf16 row-major out. SWZ=1: K-swizzled out [tok>>5][hd>>3][tok&31][hd&7]
template<int SWZ>
__global__ __launch_bounds__(256) void gemm_nt(
    const unsigned short* __restrict__ A, const unsigned short* __restrict__ W,
    const float* __restrict__ bias, unsigned short* __restrict__ out, int M, int N, int K)
{
    __shared__ short As[4][64][8];
    __shared__ short Ws[4][64][8];
    const int tid = threadIdx.x;
    const int wave = tid >> 6, lane = tid & 63;
    const int lr = lane & 15, lc = lane >> 4;
    const int m0 = blockIdx.x * 64, n0 = blockIdx.y * 64;

    floatx4 acc[4] = {};
    const int srow = tid >> 2, sch = tid & 3;
    const unsigned short* Ag = A + (long)(m0 + srow) * K + sch * 8;
    const unsigned short* Wg = W + (long)(n0 + srow) * K + sch * 8;

    for (int k0 = 0; k0 < K; k0 += 32) {
        *(short8*)&As[sch][srow][0] = *(const short8*)(Ag + k0);
        *(short8*)&Ws[sch][srow][0] = *(const short8*)(Wg + k0);
        __syncthreads();
        short8 a = *(short8*)&As[lc][wave * 16 + lr][0];
#pragma unroll
        for (int s = 0; s < 4; s++) {
            short8 b = *(short8*)&Ws[lc][s * 16 + lr][0];
            acc[s] = __builtin_amdgcn_mfma_f32_16x16x32_bf16(a, b, acc[s], 0, 0, 0);
        }
        __syncthreads();
    }

#pragma unroll
    for (int s = 0; s < 4; s++) {
        int h = n0 + s * 16 + lr;
        float bv = bias[h];
        int tok0 = m0 + wave * 16 + lc * 4;
#pragma unroll
        for (int r = 0; r < 4; r++) {
            int tok = tok0 + r;
            if (SWZ)
                out[(tok >> 5) * 4096 + (h >> 3) * 256 + (tok & 31) * 8 + (h & 7)] =
                    f2bf(acc[s][r] + bv);
            else
                out[(long)tok * N + h] = f2bf(acc[s][r] + bv);
        }
    }
}

// ---------------- 128-tile NT GEMM, global_load_lds staging ----------------
// MODE 0: f32 out row-major; MODE 2: V-swizzled bf16 out
template<int MODE>
__global__ __launch_bounds__(256) void gemm128_nt(
    const unsigned short* __restrict__ A, const unsigned short* __restrict__ W,
    const float* __restrict__ bias, void* __restrict__ out, int M, int N, int K)
{
    __shared__ short As[128][4][8]; // [row][k-chunk][8]
    __shared__ short Ws[128][4][8];
    const int tid = threadIdx.x, wave = tid >> 6, lane = tid & 63;
    const int lr = lane & 15, lc = lane >> 4;
    const int wm = (wave >> 1) * 64, wn = (wave & 1) * 64;
    const int m0 = blockIdx.x * 128, n0 = blockIdx.y * 128;

    floatx4 acc[4][4] = {};

    const int srow = lane >> 2, sch = lane & 3;
    const unsigned short* Ag0 = A + (long)(m0 + wave * 32 + srow) * K + sch * 8;
    const unsigned short* Ag1 = Ag0 + (long)16 * K;
    const unsigned short* Wg0 = W + (long)(n0 + wave * 32 + srow) * K + sch * 8;
    const unsigned short* Wg1 = Wg0 + (long)16 * K;
    short* lA0 = &As[wave * 32][0][0];
    short* lA1 = &As[wave * 32 + 16][0][0];
    short* lW0 = &Ws[wave * 32][0][0];
    short* lW1 = &Ws[wave * 32 + 16][0][0];

    for (int k0 = 0; k0 < K; k0 += 32) {
        async16(Ag0 + k0, lA0);
        async16(Ag1 + k0, lA1);
        async16(Wg0 + k0, lW0);
        async16(Wg1 + k0, lW1);
        __syncthreads();
        short8 af[4], bfg[4];
#pragma unroll
        for (int i = 0; i < 4; i++) af[i]  = *(short8*)&As[wm + i * 16 + lr][lc][0];
#pragma unroll
        for (int j = 0; j < 4; j++) bfg[j] = *(short8*)&Ws[wn + j * 16 + lr][lc][0];
#pragma unroll
        for (int i = 0; i < 4; i++)
#pragma unroll
            for (int j = 0; j < 4; j++)
                acc[i][j] = __builtin_amdgcn_mfma_f32_16x16x32_bf16(af[i], bfg[j], acc[i][j], 0, 0, 0);
        __syncthreads();
    }

#pragma unroll
    for (int i = 0; i < 4; i++) {
        int t0 = m0 + wm + i * 16 + lc * 4;
#pragma unroll
        for (int j = 0; j < 4; j++) {
            int c = n0 + wn + j * 16 + lr;
            float bv = bias[c];
            if (MODE == 0) {
                float* o = (float*)out;
#pragma unroll
                for (int r = 0; r < 4; r++) o[(long)(t0 + r) * N + c] = acc[i][j][r] + bv;
            } else {
                unsigned short* o = (unsigned short*)out;
                ushort4 pk;
                pk.x = f2bf(acc[i][j][0] + bv); pk.y = f2bf(acc[i][j][1] + bv);
                pk.z = f2bf(acc[i][j][2] + bv); pk.w = f2bf(acc[i][j][3] + bv);
                long off = (long)(c >> 8) * 2097152 + (t0 >> 5) * 8192 +
                           ((t0 & 31) >> 3) * 2048 + (c & 255) * 8 + (t0 & 7);
                *(ushort4*)&o[off] = pk;
            }
        }
    }
}

// ---------------- fused attention: partial O = exp(QK^T*scale) @ V + rowsum ----------------
// grid (m-tiles=64, c-tiles=4, n-split=2); block: 4 waves x 32 rows = 128 rows, 256 c.
// K_swz: [ntile][ch16][row32][8] 8KB tiles; V_swz: [cblk][ntile][ch4][c256][8] 16KB tiles.
// Double-buffered staging, one barrier per n-tile. S computed transposed (A=K, B=Q) so
// each lane holds 4 consecutive n-cols of one q-row -> b64 P-writes.
__global__ __launch_bounds__(256) void attn_pv(
    const unsigned short* __restrict__ qb, const unsigned short* __restrict__ ksw,
    const unsigned short* __restrict__ vsw,
    unsigned short* __restrict__ Oa, unsigned short* __restrict__ Ob,
    float* __restrict__ la, float* __restrict__ lb)
{
    __shared__ short Ks[2][16][32][8];  // 16 KB
    __shared__ short Vs[2][4][256][8];  // 32 KB
    __shared__ short Ps[4][32][40];     // 10 KB [wave][m 32][n 32 + pad 8]

    const int tid = threadIdx.x, wave = tid >> 6, lane = tid & 63;
    const int lr = lane & 15, lc = lane >> 4;
    const int m0 = blockIdx.x * 128, cblk = blockIdx.y;
    const int mw = m0 + wave * 32;
    const int nt0 = blockIdx.z * 128; // 32-wide n-tiles
    unsigned short* Op = blockIdx.z ? Ob : Oa;
    float* ls = blockIdx.z ? lb : la;
    const float cexp = (float)(0.08838834764831845 * 1.4426950408889634); // scale*log2e

    short8 qf[2][4];
#pragma unroll
    for (int i = 0; i < 2; i++)
#pragma unroll
        for (int kk = 0; kk < 4; kk++)
            qf[i][kk] = *(const short8*)&qb[(mw + i * 16 + lr) * HDIM + kk * 32 + lc * 8];

    floatx4 acc[2][16] = {};
    float lsum[2] = {0.f, 0.f};

    // contiguous staging: each wave-load = 64 lanes x 16 B = 1 KB contiguous
    const unsigned short* kg[2]; short* kl[2];
#pragma unroll
    for (int t = 0; t < 2; t++) {
        int L = wave * 2 + t;
        kg[t] = ksw + L * 512 + lane * 8;
        kl[t] = &Ks[0][0][0][0] + L * 512;
    }
    const unsigned short* vg[4]; short* vl[4];
#pragma unroll
    for (int t = 0; t < 4; t++) {
        int L = wave * 4 + t;
        vg[t] = vsw + (long)cblk * 2097152 + L * 512 + lane * 8;
        vl[t] = &Vs[0][0][0][0] + L * 512;
    }

    // prologue: stage tile nt0 into buffer 0
#pragma unroll
    for (int t = 0; t < 2; t++) async16(kg[t] + (long)nt0 * 4096, kl[t]);
#pragma unroll
    for (int t = 0; t < 4; t++) async16(vg[t] + (long)nt0 * 8192, vl[t]);

    for (int it = 0; it < 128; ++it) {
        const int buf = it & 1;
        __syncthreads(); // drains vmem -> buf ready; all waves done with buf^1
        if (it + 1 < 128) {
            long nt = nt0 + it + 1;
#pragma unroll
            for (int t = 0; t < 2; t++) async16(kg[t] + nt * 4096, kl[t] + (buf ^ 1) * 4096);
#pragma unroll
            for (int t = 0; t < 4; t++) async16(vg[t] + nt * 8192, vl[t] + (buf ^ 1) * 8192);
        }

        // S^T tiles: st[i][sub] = mfma(K-frag, Q-frag); lane: q-row=lr, n-cols=sub*16+lc*4+r
        floatx4 st[2][2] = {};
#pragma unroll
        for (int kk = 0; kk < 4; kk++) {
            short8 kf0 = *(short8*)&Ks[buf][kk * 4 + lc][lr][0];
            short8 kf1 = *(short8*)&Ks[buf][kk * 4 + lc][16 + lr][0];
            st[0][0] = __builtin_amdgcn_mfma_f32_16x16x32_bf16(kf0, qf[0][kk], st[0][0], 0, 0, 0);
            st[0][1] = __builtin_amdgcn_mfma_f32_16x16x32_bf16(kf1, qf[0][kk], st[0][1], 0, 0, 0);
            st[1][0] = __builtin_amdgcn_mfma_f32_16x16x32_bf16(kf0, qf[1][kk], st[1][0], 0, 0, 0);
            st[1][1] = __builtin_amdgcn_mfma_f32_16x16x32_bf16(kf1, qf[1][kk], st[1][1], 0, 0, 0);
        }
        // P = exp2(s*c) -> packed b64 writes into A-layout Ps
#pragma unroll
        for (int i = 0; i < 2; i++)
#pragma unroll
            for (int sub = 0; sub < 2; sub++) {
                ushort4v pk;
#pragma unroll
                for (int r = 0; r < 4; r++) {
                    float p = __builtin_amdgcn_exp2f(st[i][sub][r] * cexp);
                    lsum[i] += p;
                    pk[r] = f2bf_fast(p);
                }
                *(ushort4v*)&Ps[wave][i * 16 + lr][sub * 16 + lc * 4] = pk;
            }
        // PV: O[32x256] += P[32x32] @ V[32x256]
        short8 ap0 = *(short8*)&Ps[wave][lr][lc * 8];
        short8 ap1 = *(short8*)&Ps[wave][16 + lr][lc * 8];
#pragma unroll
        for (int cs = 0; cs < 16; cs++) {
            short8 b = *(short8*)&Vs[buf][lc][cs * 16 + lr][0];
            acc[0][cs] = __builtin_amdgcn_mfma_f32_16x16x32_bf16(ap0, b, acc[0][cs], 0, 0, 0);
            acc[1][cs] = __builtin_amdgcn_mfma_f32_16x16x32_bf16(ap1, b, acc[1][cs], 0, 0, 0);
        }
    }

    // unnormalized partial O
#pragma unroll
    for (int i = 0; i < 2; i++)
#pragma unroll
        for (int cs = 0; cs < 16; cs++) {
            int c = cblk * 256 + cs * 16 + lr;
#pragma unroll
            for (int r = 0; r < 4; r++)
                Op[(long)(mw + i * 16 + lc * 4 + r) * CDIM + c] = f2bf(acc[i][cs][r]);
        }
    // partial row sums (q-row = i*16+lr; reduce over lc lanes)
    if (blockIdx.y == 0) {
#pragma unroll
        for (int i = 0; i < 2; i++) {
            lsum[i] += __shfl_xor(lsum[i], 16);
            lsum[i] += __shfl_xor(lsum[i], 32);
        }
        if (lc == 0) {
#pragma unroll
            for (int i = 0; i < 2; i++) ls[mw + i * 16 + lr] = lsum[i];
        }
    }
}

// ---------------- combine: attn = (Oa + Ob) / (la + lb), in place over Ob ----------------
__global__ __launch_bounds__(256) void combine_attn(
    const unsigned short* __restrict__ Oa, unsigned short* __restrict__ Ob,
    const float* __restrict__ la, const float* __restrict__ lb)
{
    int i = blockIdx.x * blockDim.x + threadIdx.x; // one per 8 elems
    int row = i >> 7;                              // CDIM/8 = 128
    float inv = 1.0f / (la[row] + lb[row]);
    short8 a = ((const short8*)Oa)[i];
    short8 b = ((const short8*)Ob)[i];
    short8 o;
#pragma unroll
    for (int e = 0; e < 8; e++) o[e] = (short)f2bf((bf2f(a[e]) + bf2f(b[e])) * inv);
    ((short8*)Ob)[i] = o;
}

extern "C" void kernel_launch(void* const* d_in, const int* in_sizes, int n_in,
                              void* d_out, int out_size, void* d_ws, size_t ws_size,
                              hipStream_t stream) {
    const float* x  = (const float*)d_in[0];
    const float* Wq = (const float*)d_in[1];
    const float* bq = (const float*)d_in[2];
    const float* Wk = (const float*)d_in[3];
    const float* bk = (const float*)d_in[4];
    const float* Wv = (const float*)d_in[5];
    const float* bv = (const float*)d_in[6];
    const float* Wo = (const float*)d_in[7];
    const float* bo = (const float*)d_in[8];

    char* ws = (char*)d_ws;
    unsigned short* x_bf   = (unsigned short*)(ws + 0);          // 16 MB (reused as Oa)
    unsigned short* wq_bf  = (unsigned short*)(ws + 16777216);   // 256 KB
    unsigned short* wk_bf  = (unsigned short*)(ws + 17039360);   // 256 KB
    unsigned short* wv_bf  = (unsigned short*)(ws + 17301504);   // 2 MB
    unsigned short* wo_bf  = (unsigned short*)(ws + 19398656);   // 2 MB
    unsigned short* q_bf   = (unsigned short*)(ws + 21495808);   // 2 MB
    unsigned short* k_swz  = (unsigned short*)(ws + 23592960);   // 2 MB (K swizzled)
    unsigned short* v_swz  = (unsigned short*)(ws + 25690112);   // 16 MB (V swizzled)
    unsigned short* attn_bf= (unsigned short*)(ws + 42467328);   // 16 MB (Ob, combined in place)
    float* lsum_a          = (float*)(ws + 59244544);            // 32 KB
    float* lsum_b          = (float*)(ws + 59277312);            // 32 KB

    // casts to bf16
    cast_f32_bf16<<<8192, 256, 0, stream>>>(x,  x_bf,  2097152);
    cast_f32_bf16<<<128,  256, 0, stream>>>(Wq, wq_bf, 32768);
    cast_f32_bf16<<<128,  256, 0, stream>>>(Wk, wk_bf, 32768);
    cast_f32_bf16<<<1024, 256, 0, stream>>>(Wv, wv_bf, 262144);
    cast_f32_bf16<<<1024, 256, 0, stream>>>(Wo, wo_bf, 262144);

    // projections
    gemm_nt<0><<<dim3(128, 2), 256, 0, stream>>>(x_bf, wq_bf, bq, q_bf, NTOK, HDIM, CDIM);
    gemm_nt<1><<<dim3(128, 2), 256, 0, stream>>>(x_bf, wk_bf, bk, k_swz, NTOK, HDIM, CDIM);
    gemm128_nt<2><<<dim3(64, 8), 256, 0, stream>>>(x_bf, wv_bf, bv, v_swz, NTOK, CDIM, CDIM);

    // fused attention (split-n over gridDim.z); Oa overlays dead x_bf
    attn_pv<<<dim3(64, 4, 2), 256, 0, stream>>>(q_bf, k_swz, v_swz,
                                                x_bf, attn_bf, lsum_a, lsum_b);
    combine_attn<<<4096, 256, 0, stream>>>(x_bf, attn_bf, lsum_a, lsum_b);

    // output projection (fp32 out)
    gemm128_nt<0><<<dim3(64, 8), 256, 0, stream>>>(attn_bf, wo_bf, bo, d_out, NTOK, CDIM, CDIM);
}

// Round 6
// 442.203 us; speedup vs baseline: 2.7821x; 1.3541x over previous
//
#include <hip/hip_runtime.h>

#define NTOK 8192
#define CDIM 1024
#define HDIM 128

typedef __attribute__((ext_vector_type(8))) short short8;
typedef __attribute__((ext_vector_type(4))) float floatx4;
typedef __attribute__((ext_vector_type(4))) unsigned short ushort4v;

__device__ inline unsigned short f2bf(float f) {
    union { float f; unsigned u; } v; v.f = f;
    unsigned r = v.u + 0x7fffu + ((v.u >> 16) & 1u);
    return (unsigned short)(r >> 16);
}
__device__ inline unsigned short f2bf_fast(float f) {
    union { float f; unsigned u; } v; v.f = f;
    return (unsigned short)((v.u + 0x8000u) >> 16);
}
__device__ inline float bf2f(short s) {
    union { unsigned u; float f; } v;
    v.u = ((unsigned)(unsigned short)s) << 16;
    return v.f;
}
__device__ inline void async16(const unsigned short* g, short* l) {
    __builtin_amdgcn_global_load_lds(
        (const __attribute__((address_space(1))) unsigned*)g,
        (__attribute__((address_space(3))) unsigned*)l, 16, 0, 0);
}

// ---------------- cast fp32 -> bf16, 4 elems/thread ----------------
__global__ void cast_f32_bf16(const float* __restrict__ in,
                              unsigned short* __restrict__ out, int n4) {
    int i = blockIdx.x * blockDim.x + threadIdx.x;
    if (i < n4) {
        float4 v = ((const float4*)in)[i];
        ushort4 o;
        o.x = f2bf(v.x); o.y = f2bf(v.y); o.z = f2bf(v.z); o.w = f2bf(v.w);
        ((ushort4*)out)[i] = o;
    }
}

// ---------------- 64-tile NT GEMM (narrow N: q/k proj) ----------------
// SWZ=0: bf16 row-major out. SWZ=1: K-swizzled out [tok>>5][hd>>3][tok&31][hd&7]
template<int SWZ>
__global__ __launch_bounds__(256) void gemm_nt(
    const unsigned short* __restrict__ A, const unsigned short* __restrict__ W,
    const float* __restrict__ bias, unsigned short* __restrict__ out, int M, int N, int K)
{
    __shared__ short As[4][64][8];
    __shared__ short Ws[4][64][8];
    const int tid = threadIdx.x;
    const int wave = tid >> 6, lane = tid & 63;
    const int lr = lane & 15, lc = lane >> 4;
    const int m0 = blockIdx.x * 64, n0 = blockIdx.y * 64;

    floatx4 acc[4] = {};
    const int srow = tid >> 2, sch = tid & 3;
    const unsigned short* Ag = A + (long)(m0 + srow) * K + sch * 8;
    const unsigned short* Wg = W + (long)(n0 + srow) * K + sch * 8;

    for (int k0 = 0; k0 < K; k0 += 32) {
        *(short8*)&As[sch][srow][0] = *(const short8*)(Ag + k0);
        *(short8*)&Ws[sch][srow][0] = *(const short8*)(Wg + k0);
        __syncthreads();
        short8 a = *(short8*)&As[lc][wave * 16 + lr][0];
#pragma unroll
        for (int s = 0; s < 4; s++) {
            short8 b = *(short8*)&Ws[lc][s * 16 + lr][0];
            acc[s] = __builtin_amdgcn_mfma_f32_16x16x32_bf16(a, b, acc[s], 0, 0, 0);
        }
        __syncthreads();
    }

#pragma unroll
    for (int s = 0; s < 4; s++) {
        int h = n0 + s * 16 + lr;
        float bv = bias[h];
        int tok0 = m0 + wave * 16 + lc * 4;
#pragma unroll
        for (int r = 0; r < 4; r++) {
            int tok = tok0 + r;
            if (SWZ)
                out[(tok >> 5) * 4096 + (h >> 3) * 256 + (tok & 31) * 8 + (h & 7)] =
                    f2bf(acc[s][r] + bv);
            else
                out[(long)tok * N + h] = f2bf(acc[s][r] + bv);
        }
    }
}

// ---------------- 128-tile NT GEMM, global_load_lds staging ----------------
// MODE 0: f32 out row-major; MODE 2: V-swizzled bf16 out
template<int MODE>
__global__ __launch_bounds__(256) void gemm128_nt(
    const unsigned short* __restrict__ A, const unsigned short* __restrict__ W,
    const float* __restrict__ bias, void* __restrict__ out, int M, int N, int K)
{
    __shared__ short As[128][4][8]; // [row][k-chunk][8]
    __shared__ short Ws[128][4][8];
    const int tid = threadIdx.x, wave = tid >> 6, lane = tid & 63;
    const int lr = lane & 15, lc = lane >> 4;
    const int wm = (wave >> 1) * 64, wn = (wave & 1) * 64;
    const int m0 = blockIdx.x * 128, n0 = blockIdx.y * 128;

    floatx4 acc[4][4] = {};

    const int srow = lane >> 2, sch = lane & 3;
    const unsigned short* Ag0 = A + (long)(m0 + wave * 32 + srow) * K + sch * 8;
    const unsigned short* Ag1 = Ag0 + (long)16 * K;
    const unsigned short* Wg0 = W + (long)(n0 + wave * 32 + srow) * K + sch * 8;
    const unsigned short* Wg1 = Wg0 + (long)16 * K;
    short* lA0 = &As[wave * 32][0][0];
    short* lA1 = &As[wave * 32 + 16][0][0];
    short* lW0 = &Ws[wave * 32][0][0];
    short* lW1 = &Ws[wave * 32 + 16][0][0];

    for (int k0 = 0; k0 < K; k0 += 32) {
        async16(Ag0 + k0, lA0);
        async16(Ag1 + k0, lA1);
        async16(Wg0 + k0, lW0);
        async16(Wg1 + k0, lW1);
        __syncthreads();
        short8 af[4], bfg[4];
#pragma unroll
        for (int i = 0; i < 4; i++) af[i]  = *(short8*)&As[wm + i * 16 + lr][lc][0];
#pragma unroll
        for (int j = 0; j < 4; j++) bfg[j] = *(short8*)&Ws[wn + j * 16 + lr][lc][0];
#pragma unroll
        for (int i = 0; i < 4; i++)
#pragma unroll
            for (int j = 0; j < 4; j++)
                acc[i][j] = __builtin_amdgcn_mfma_f32_16x16x32_bf16(af[i], bfg[j], acc[i][j], 0, 0, 0);
        __syncthreads();
    }

#pragma unroll
    for (int i = 0; i < 4; i++) {
        int t0 = m0 + wm + i * 16 + lc * 4;
#pragma unroll
        for (int j = 0; j < 4; j++) {
            int c = n0 + wn + j * 16 + lr;
            float bv = bias[c];
            if (MODE == 0) {
                float* o = (float*)out;
#pragma unroll
                for (int r = 0; r < 4; r++) o[(long)(t0 + r) * N + c] = acc[i][j][r] + bv;
            } else {
                unsigned short* o = (unsigned short*)out;
                ushort4 pk;
                pk.x = f2bf(acc[i][j][0] + bv); pk.y = f2bf(acc[i][j][1] + bv);
                pk.z = f2bf(acc[i][j][2] + bv); pk.w = f2bf(acc[i][j][3] + bv);
                long off = (long)(c >> 8) * 2097152 + (t0 >> 5) * 8192 +
                           ((t0 & 31) >> 3) * 2048 + (c & 255) * 8 + (t0 & 7);
                *(ushort4*)&o[off] = pk;
            }
        }
    }
}

// ---------------- fused attention: partial O = exp(QK^T*scale) @ V + rowsum ----------------
// grid (m-tiles=32, c-tiles=4, n-split=2); block: 4 waves, each wave 64 q-rows x 256 c.
// n-tile per barrier = 64 (two 32-n halves). 1 block/CU, 1 wave/SIMD (big acc).
// K_swz: [ntile32][ch16][row32][8] 8KB; V_swz: [cblk][ntile32][ch4][c256][8] 16KB.
__global__ __launch_bounds__(256, 1) void attn_pv(
    const unsigned short* __restrict__ qb, const unsigned short* __restrict__ ksw,
    const unsigned short* __restrict__ vsw,
    unsigned short* __restrict__ Oa, unsigned short* __restrict__ Ob,
    float* __restrict__ la, float* __restrict__ lb)
{
    __shared__ short Ks[2][2][16][32][8];  // [buf][half] 8KB each = 32 KB
    __shared__ short Vs[2][2][4][256][8];  // [buf][half] 16KB each = 64 KB
    __shared__ short Ps[4][64][40];        // 20 KB [wave][m 64][n 32 + pad]

    const int tid = threadIdx.x, wave = tid >> 6, lane = tid & 63;
    const int lr = lane & 15, lc = lane >> 4;
    const int m0 = blockIdx.x * 256, cblk = blockIdx.y;
    const int mw = m0 + wave * 64;
    const int nt0 = blockIdx.z * 128; // in 32-n tiles; 64 iters x 2 tiles
    unsigned short* Op = blockIdx.z ? Ob : Oa;
    float* ls = blockIdx.z ? lb : la;
    const float cexp = (float)(0.08838834764831845 * 1.4426950408889634); // scale*log2e

    // Q fragments for 4 m-subtiles (B-operand of S^T mfma)
    short8 qf[4][4];
#pragma unroll
    for (int ms = 0; ms < 4; ms++)
#pragma unroll
        for (int kk = 0; kk < 4; kk++)
            qf[ms][kk] = *(const short8*)&qb[(mw + ms * 16 + lr) * HDIM + kk * 32 + lc * 8];

    floatx4 acc[4][16] = {};
    float lsum[4] = {};

    // staging: every wave-load = 64 lanes x 16 B = 1 KB contiguous
    const unsigned short* kg[2];
    short* const klb = &Ks[0][0][0][0][0];
#pragma unroll
    for (int t = 0; t < 2; t++) kg[t] = ksw + (wave * 2 + t) * 512 + lane * 8;
    const unsigned short* vg[4];
    short* const vlb = &Vs[0][0][0][0][0];
#pragma unroll
    for (int t = 0; t < 4; t++)
        vg[t] = vsw + (long)cblk * 2097152 + (wave * 4 + t) * 512 + lane * 8;

    // prologue: stage iteration 0 (both halves) into buf 0
#pragma unroll
    for (int h = 0; h < 2; h++) {
        long nt = nt0 + h;
#pragma unroll
        for (int t = 0; t < 2; t++)
            async16(kg[t] + nt * 4096, klb + h * 4096 + (wave * 2 + t) * 512);
#pragma unroll
        for (int t = 0; t < 4; t++)
            async16(vg[t] + nt * 8192, vlb + h * 8192 + (wave * 4 + t) * 512);
    }

    for (int it = 0; it < 64; ++it) {
        const int buf = it & 1;
        __syncthreads(); // drains vmem -> buf ready; all waves done with buf^1
        if (it + 1 < 64) {
#pragma unroll
            for (int h = 0; h < 2; h++) {
                long nt = nt0 + 2 * (it + 1) + h;
#pragma unroll
                for (int t = 0; t < 2; t++)
                    async16(kg[t] + nt * 4096,
                            klb + (buf ^ 1) * 8192 + h * 4096 + (wave * 2 + t) * 512);
#pragma unroll
                for (int t = 0; t < 4; t++)
                    async16(vg[t] + nt * 8192,
                            vlb + (buf ^ 1) * 16384 + h * 8192 + (wave * 4 + t) * 512);
            }
        }

#pragma unroll
        for (int h = 0; h < 2; h++) {
            // S^T: st[ms][sub] = K[n-sub] @ Q[ms]^T ; lane: q-row=lr, n=sub*16+lc*4+r
            floatx4 st[4][2] = {};
#pragma unroll
            for (int kk = 0; kk < 4; kk++) {
                short8 kf0 = *(short8*)&Ks[buf][h][kk * 4 + lc][lr][0];
                short8 kf1 = *(short8*)&Ks[buf][h][kk * 4 + lc][16 + lr][0];
#pragma unroll
                for (int ms = 0; ms < 4; ms++) {
                    st[ms][0] = __builtin_amdgcn_mfma_f32_16x16x32_bf16(kf0, qf[ms][kk], st[ms][0], 0, 0, 0);
                    st[ms][1] = __builtin_amdgcn_mfma_f32_16x16x32_bf16(kf1, qf[ms][kk], st[ms][1], 0, 0, 0);
                }
            }
            // P = exp2(s*c) -> packed b64 writes into A-layout Ps
#pragma unroll
            for (int ms = 0; ms < 4; ms++)
#pragma unroll
                for (int sub = 0; sub < 2; sub++) {
                    ushort4v pk;
#pragma unroll
                    for (int r = 0; r < 4; r++) {
                        float p = __builtin_amdgcn_exp2f(st[ms][sub][r] * cexp);
                        lsum[ms] += p;
                        pk[r] = f2bf_fast(p);
                    }
                    *(ushort4v*)&Ps[wave][ms * 16 + lr][sub * 16 + lc * 4] = pk;
                }
            // PV: O[64x256] += P[64x32] @ V[32x256]
            short8 ap[4];
#pragma unroll
            for (int ms = 0; ms < 4; ms++) ap[ms] = *(short8*)&Ps[wave][ms * 16 + lr][lc * 8];
#pragma unroll
            for (int csh = 0; csh < 2; csh++) {
                short8 bv[8];
#pragma unroll
                for (int cs = 0; cs < 8; cs++)
                    bv[cs] = *(short8*)&Vs[buf][h][lc][(csh * 8 + cs) * 16 + lr][0];
#pragma unroll
                for (int ms = 0; ms < 4; ms++)
#pragma unroll
                    for (int cs = 0; cs < 8; cs++)
                        acc[ms][csh * 8 + cs] =
                            __builtin_amdgcn_mfma_f32_16x16x32_bf16(ap[ms], bv[cs], acc[ms][csh * 8 + cs], 0, 0, 0);
            }
        }
    }

    // unnormalized partial O
#pragma unroll
    for (int ms = 0; ms < 4; ms++)
#pragma unroll
        for (int cs = 0; cs < 16; cs++) {
            int c = cblk * 256 + cs * 16 + lr;
#pragma unroll
            for (int r = 0; r < 4; r++)
                Op[(long)(mw + ms * 16 + lc * 4 + r) * CDIM + c] = f2bf(acc[ms][cs][r]);
        }
    // partial row sums (q-row = ms*16+lr; reduce over lc lanes)
    if (blockIdx.y == 0) {
#pragma unroll
        for (int ms = 0; ms < 4; ms++) {
            lsum[ms] += __shfl_xor(lsum[ms], 16);
            lsum[ms] += __shfl_xor(lsum[ms], 32);
        }
        if (lc == 0) {
#pragma unroll
            for (int ms = 0; ms < 4; ms++) ls[mw + ms * 16 + lr] = lsum[ms];
        }
    }
}

// ---------------- combine: attn = (Oa + Ob) / (la + lb), in place over Ob ----------------
__global__ __launch_bounds__(256) void combine_attn(
    const unsigned short* __restrict__ Oa, unsigned short* __restrict__ Ob,
    const float* __restrict__ la, const float* __restrict__ lb)
{
    int i = blockIdx.x * blockDim.x + threadIdx.x; // one per 8 elems
    int row = i >> 7;                              // CDIM/8 = 128
    float inv = 1.0f / (la[row] + lb[row]);
    short8 a = ((const short8*)Oa)[i];
    short8 b = ((const short8*)Ob)[i];
    short8 o;
#pragma unroll
    for (int e = 0; e < 8; e++) o[e] = (short)f2bf((bf2f(a[e]) + bf2f(b[e])) * inv);
    ((short8*)Ob)[i] = o;
}

extern "C" void kernel_launch(void* const* d_in, const int* in_sizes, int n_in,
                              void* d_out, int out_size, void* d_ws, size_t ws_size,
                              hipStream_t stream) {
    const float* x  = (const float*)d_in[0];
    const float* Wq = (const float*)d_in[1];
    const float* bq = (const float*)d_in[2];
    const float* Wk = (const float*)d_in[3];
    const float* bk = (const float*)d_in[4];
    const float* Wv = (const float*)d_in[5];
    const float* bv = (const float*)d_in[6];
    const float* Wo = (const float*)d_in[7];
    const float* bo = (const float*)d_in[8];

    char* ws = (char*)d_ws;
    unsigned short* x_bf   = (unsigned short*)(ws + 0);          // 16 MB (reused as Oa)
    unsigned short* wq_bf  = (unsigned short*)(ws + 16777216);   // 256 KB
    unsigned short* wk_bf  = (unsigned short*)(ws + 17039360);   // 256 KB
    unsigned short* wv_bf  = (unsigned short*)(ws + 17301504);   // 2 MB
    unsigned short* wo_bf  = (unsigned short*)(ws + 19398656);   // 2 MB
    unsigned short* q_bf   = (unsigned short*)(ws + 21495808);   // 2 MB
    unsigned short* k_swz  = (unsigned short*)(ws + 23592960);   // 2 MB (K swizzled)
    unsigned short* v_swz  = (unsigned short*)(ws + 25690112);   // 16 MB (V swizzled)
    unsigned short* attn_bf= (unsigned short*)(ws + 42467328);   // 16 MB (Ob, combined in place)
    float* lsum_a          = (float*)(ws + 59244544);            // 32 KB
    float* lsum_b          = (float*)(ws + 59277312);            // 32 KB

    // casts to bf16
    cast_f32_bf16<<<8192, 256, 0, stream>>>(x,  x_bf,  2097152);
    cast_f32_bf16<<<128,  256, 0, stream>>>(Wq, wq_bf, 32768);
    cast_f32_bf16<<<128,  256, 0, stream>>>(Wk, wk_bf, 32768);
    cast_f32_bf16<<<1024, 256, 0, stream>>>(Wv, wv_bf, 262144);
    cast_f32_bf16<<<1024, 256, 0, stream>>>(Wo, wo_bf, 262144);

    // projections
    gemm_nt<0><<<dim3(128, 2), 256, 0, stream>>>(x_bf, wq_bf, bq, q_bf, NTOK, HDIM, CDIM);
    gemm_nt<1><<<dim3(128, 2), 256, 0, stream>>>(x_bf, wk_bf, bk, k_swz, NTOK, HDIM, CDIM);
    gemm128_nt<2><<<dim3(64, 8), 256, 0, stream>>>(x_bf, wv_bf, bv, v_swz, NTOK, CDIM, CDIM);

    // fused attention (split-n over gridDim.z); Oa overlays dead x_bf
    attn_pv<<<dim3(32, 4, 2), 256, 0, stream>>>(q_bf, k_swz, v_swz,
                                                x_bf, attn_bf, lsum_a, lsum_b);
    combine_attn<<<4096, 256, 0, stream>>>(x_bf, attn_bf, lsum_a, lsum_b);

    // output projection (fp32 out)
    gemm128_nt<0><<<dim3(64, 8), 256, 0, stream>>>(attn_bf, wo_bf, bo, d_out, NTOK, CDIM, CDIM);
}